// Round 4
// baseline (583.093 us; speedup 1.0000x reference)
//
#include <hip/hip_runtime.h>
#include <cstdint>

// ---------------------------------------------------------------------------
// Threefry-2x32, 20 rounds — exact JAX schedule (jax/_src/prng.py)
// ---------------------------------------------------------------------------
static __host__ __device__ inline void tf2x32(uint32_t k0, uint32_t k1,
                                              uint32_t x0, uint32_t x1,
                                              uint32_t &o0, uint32_t &o1) {
  uint32_t ks2 = k0 ^ k1 ^ 0x1BD11BDAu;
  x0 += k0; x1 += k1;
#define TF_R(r) do { x0 += x1; x1 = (x1 << (r)) | (x1 >> (32 - (r))); x1 ^= x0; } while (0)
  TF_R(13); TF_R(15); TF_R(26); TF_R(6);
  x0 += k1; x1 += ks2 + 1u;
  TF_R(17); TF_R(29); TF_R(16); TF_R(24);
  x0 += ks2; x1 += k0 + 2u;
  TF_R(13); TF_R(15); TF_R(26); TF_R(6);
  x0 += k0; x1 += k1 + 3u;
  TF_R(17); TF_R(29); TF_R(16); TF_R(24);
  x0 += k1; x1 += ks2 + 4u;
  TF_R(13); TF_R(15); TF_R(26); TF_R(6);
  x0 += ks2; x1 += k0 + 5u;
#undef TF_R
  o0 = x0; o1 = x1;
}

// XLA's f32 erf_inv expansion (Giles poly, w = -log1p(-x*x)).
__device__ __forceinline__ float erfinv_xla_f32(float x) {
  float w = -log1pf(-x * x);
  float p;
  if (w < 5.0f) {
    w -= 2.5f;
    p = 2.81022636e-08f;
    p = fmaf(p, w, 3.43273939e-07f);
    p = fmaf(p, w, -3.5233877e-06f);
    p = fmaf(p, w, -4.39150654e-06f);
    p = fmaf(p, w, 0.00021858087f);
    p = fmaf(p, w, -0.00125372503f);
    p = fmaf(p, w, -0.00417768164f);
    p = fmaf(p, w, 0.246640727f);
    p = fmaf(p, w, 1.50140941f);
  } else {
    w = sqrtf(w) - 3.0f;
    p = -0.000200214257f;
    p = fmaf(p, w, 0.000100950558f);
    p = fmaf(p, w, 0.00134934322f);
    p = fmaf(p, w, -0.00367342844f);
    p = fmaf(p, w, 0.00573950773f);
    p = fmaf(p, w, -0.0076224613f);
    p = fmaf(p, w, 0.00943887047f);
    p = fmaf(p, w, 1.00167406f);
    p = fmaf(p, w, 2.83297682f);
  }
  return p * x;
}

__device__ __forceinline__ float noise_val(uint32_t kk0, uint32_t kk1, uint32_t idx) {
  uint32_t o0, o1;
  tf2x32(kk0, kk1, 0u, idx, o0, o1);
  uint32_t bits = o0 ^ o1;
  float u01 = __uint_as_float((bits >> 9) | 0x3f800000u) - 1.0f;
  const float LO = -0.99999994f;            // nextafter(-1f, 0f)
  float u = fmaxf(LO, fmaf(u01, 2.0f, LO)); // hi-lo rounds to exactly 2.0f
  return 0.1f * 1.41421356237f * erfinv_xla_f32(u);
}

// ---------------------------------------------------------------------------
// CSR build: counts -> 3-phase exclusive scan -> bucket fill
// ---------------------------------------------------------------------------
__global__ void zero_k(int* p, int n) {
  int i = blockIdx.x * blockDim.x + threadIdx.x;
  if (i < n) p[i] = 0;
}

// 4 edges/thread, independent atomics in flight.
__global__ void hist_k(const int* __restrict__ row, int* __restrict__ counts, int ne) {
  int base = (blockIdx.x * blockDim.x + threadIdx.x) * 4;
  if (base + 3 < ne) {
    int4 r = *(const int4*)(row + base);
    atomicAdd(&counts[r.x], 1);
    atomicAdd(&counts[r.y], 1);
    atomicAdd(&counts[r.z], 1);
    atomicAdd(&counts[r.w], 1);
  } else {
    for (int e = base; e < ne; ++e) atomicAdd(&counts[row[e]], 1);
  }
}

__global__ void blocksum_k(const int* __restrict__ counts, int* __restrict__ bsum, int n) {
  int i = blockIdx.x * 256 + threadIdx.x;
  int v = (i < n) ? counts[i] : 0;
  for (int d = 1; d < 64; d <<= 1) v += __shfl_xor(v, d);
  __shared__ int ws[4];
  if ((threadIdx.x & 63) == 0) ws[threadIdx.x >> 6] = v;
  __syncthreads();
  if (threadIdx.x == 0) bsum[blockIdx.x] = ws[0] + ws[1] + ws[2] + ws[3];
}

__global__ void scanb_k(int* __restrict__ bsum, int nb) {
  __shared__ int tmp[1024];
  int t = threadIdx.x;
  int v = (t < nb) ? bsum[t] : 0;
  tmp[t] = v;
  __syncthreads();
  for (int d = 1; d < 1024; d <<= 1) {
    int x = (t >= d) ? tmp[t - d] : 0;
    __syncthreads();
    tmp[t] += x;
    __syncthreads();
  }
  if (t < nb) bsum[t] = tmp[t] - v;  // exclusive
}

__global__ void offsets_k(const int* __restrict__ counts, const int* __restrict__ bsumExcl,
                          int* __restrict__ offsets, int* __restrict__ cursor, int n) {
  int i = blockIdx.x * 256 + threadIdx.x;
  int v = (i < n) ? counts[i] : 0;
  __shared__ int tmp[256];
  tmp[threadIdx.x] = v;
  __syncthreads();
  for (int d = 1; d < 256; d <<= 1) {
    int x = (threadIdx.x >= d) ? tmp[threadIdx.x - d] : 0;
    __syncthreads();
    tmp[threadIdx.x] += x;
    __syncthreads();
  }
  int excl = tmp[threadIdx.x] - v + bsumExcl[blockIdx.x];
  if (i < n) { offsets[i] = excl; cursor[i] = excl; }
  if (i == n - 1) offsets[n] = excl + v;
}

// 4 edges/thread: int4 loads, 4 independent atomic claims, 4 independent stores.
__global__ void fill_k(const int* __restrict__ row, const int* __restrict__ col,
                       int* __restrict__ cursor, int* __restrict__ ecol, int ne) {
  int base = (blockIdx.x * blockDim.x + threadIdx.x) * 4;
  if (base + 3 < ne) {
    int4 r = *(const int4*)(row + base);
    int4 c = *(const int4*)(col + base);
    int p0 = atomicAdd(&cursor[r.x], 1);
    int p1 = atomicAdd(&cursor[r.y], 1);
    int p2 = atomicAdd(&cursor[r.z], 1);
    int p3 = atomicAdd(&cursor[r.w], 1);
    ecol[p0] = c.x;
    ecol[p1] = c.y;
    ecol[p2] = c.z;
    ecol[p3] = c.w;
  } else {
    for (int e = base; e < ne; ++e) {
      int p = atomicAdd(&cursor[row[e]], 1);
      ecol[p] = col[e];
    }
  }
}

// ---------------------------------------------------------------------------
// Fused per-hop kernel: one wave per dest row.
// Lane split: g = lane>>4 (edge slot, 4 parallel edges), f = lane&15 (feature
// quad, float4). 8-deep unroll -> 32 edges in flight per wave.
// ---------------------------------------------------------------------------
__global__ void agg_k(const float* __restrict__ src, float* __restrict__ dst,
                      const int* __restrict__ offsets, const int* __restrict__ ecol,
                      int nn, uint32_t kk0, uint32_t kk1) {
  int w = (blockIdx.x * blockDim.x + threadIdx.x) >> 6;  // row = wave id
  int lane = threadIdx.x & 63;
  int g = lane >> 4, f = lane & 15;
  if (w >= nn) return;
  const float4* src4 = (const float4*)src;
  int beg = offsets[w], end = offsets[w + 1];
  int cnt = end - beg;
  float4 acc = make_float4(0.f, 0.f, 0.f, 0.f);
  for (int base = 0; base < cnt; base += 64) {
    int m = cnt - base; if (m > 64) m = 64;
    // coalesced load of up to 64 column indices (clamped: always valid)
    int idx = base + lane;
    int myc = ecol[beg + (idx < cnt ? idx : cnt - 1)];
    for (int j = 0; j < m; j += 32) {       // 32 edges per step (8 groups of 4)
      float4 v[8];
#pragma unroll
      for (int u = 0; u < 8; ++u) {
        int jj = j + u * 4 + g;
        int sl = jj < m ? jj : m - 1;       // clamp -> valid address
        int c = __shfl(myc, sl);
        v[u] = src4[(size_t)c * 16 + f];    // 16B gather, 8 in flight
      }
#pragma unroll
      for (int u = 0; u < 8; ++u) {
        int jj = j + u * 4 + g;
        bool ok = jj < m;
        acc.x += ok ? v[u].x : 0.f;
        acc.y += ok ? v[u].y : 0.f;
        acc.z += ok ? v[u].z : 0.f;
        acc.w += ok ? v[u].w : 0.f;
      }
    }
  }
  // cross-group reduce: sum the 4 edge-groups (lanes differing in bits 4,5)
  acc.x += __shfl_xor(acc.x, 16); acc.x += __shfl_xor(acc.x, 32);
  acc.y += __shfl_xor(acc.y, 16); acc.y += __shfl_xor(acc.y, 32);
  acc.z += __shfl_xor(acc.z, 16); acc.z += __shfl_xor(acc.z, 32);
  acc.w += __shfl_xor(acc.w, 16); acc.w += __shfl_xor(acc.w, 32);
  // fused noise (features f*4..f*4+3) + L2 norm
  uint32_t nbase = (uint32_t)(w * 64 + f * 4);
  float4 nv;
  nv.x = acc.x + noise_val(kk0, kk1, nbase + 0);
  nv.y = acc.y + noise_val(kk0, kk1, nbase + 1);
  nv.z = acc.z + noise_val(kk0, kk1, nbase + 2);
  nv.w = acc.w + noise_val(kk0, kk1, nbase + 3);
  float s = nv.x * nv.x + nv.y * nv.y + nv.z * nv.z + nv.w * nv.w;
  s += __shfl_xor(s, 1);
  s += __shfl_xor(s, 2);
  s += __shfl_xor(s, 4);
  s += __shfl_xor(s, 8);
  float inv = 1.0f / fmaxf(sqrtf(s), 1e-12f);
  if (g == 0) {
    float4 o = make_float4(nv.x * inv, nv.y * inv, nv.z * inv, nv.w * inv);
    ((float4*)dst)[(size_t)w * 16 + f] = o;  // 16 lanes x 16B = 256B store
  }
}

// Row L2-normalize for slice 0: 16 lanes per row, float4 per lane.
__global__ void l2norm_k(const float4* __restrict__ in, float4* __restrict__ out,
                         int nrows) {
  int t = blockIdx.x * blockDim.x + threadIdx.x;
  int r = t >> 4, l = t & 15;
  if (r >= nrows) return;
  float4 v = in[(size_t)r * 16 + l];
  float s = v.x * v.x + v.y * v.y + v.z * v.z + v.w * v.w;
  s += __shfl_xor(s, 1);
  s += __shfl_xor(s, 2);
  s += __shfl_xor(s, 4);
  s += __shfl_xor(s, 8);
  float inv = 1.0f / fmaxf(sqrtf(s), 1e-12f);
  v.x *= inv; v.y *= inv; v.z *= inv; v.w *= inv;
  out[(size_t)r * 16 + l] = v;
}

// ---------------------------------------------------------------------------
// Fallback (atomic scatter) — only used if ws_size is too small for CSR.
// ---------------------------------------------------------------------------
__global__ void noise_fill_k(float* __restrict__ dst, int total,
                             uint32_t kk0, uint32_t kk1) {
  int i = blockIdx.x * blockDim.x + threadIdx.x;
  if (i < total) dst[i] = noise_val(kk0, kk1, (uint32_t)i);
}

__global__ void scatter_k(const int* __restrict__ row, const int* __restrict__ col,
                          const float* __restrict__ src, float* __restrict__ dst,
                          int ne) {
  int t = blockIdx.x * blockDim.x + threadIdx.x;
  int e = t >> 4, l = t & 15;
  if (e >= ne) return;
  int r = row[e], c = col[e];
  float4 v = ((const float4*)(src + (size_t)c * 64))[l];
  float* d = dst + (size_t)r * 64 + (size_t)l * 4;
  atomicAdd(d + 0, v.x);
  atomicAdd(d + 1, v.y);
  atomicAdd(d + 2, v.z);
  atomicAdd(d + 3, v.w);
}

extern "C" void kernel_launch(void* const* d_in, const int* in_sizes, int n_in,
                              void* d_out, int out_size, void* d_ws, size_t ws_size,
                              hipStream_t stream) {
  const float* x = (const float*)d_in[0];
  const int* ei = (const int*)d_in[1];
  float* out = (float*)d_out;

  const int nn = in_sizes[0] / 64;     // 100000
  const int ne = in_sizes[1] / 2;      // 1600000
  const int total = nn * 64;
  const int* row = ei;
  const int* col = ei + ne;

  // Per-hop fold_in keys: threefry2x32((0,42), (0,k)) — host precompute.
  uint32_t fk0[3], fk1[3];
  for (int k = 0; k < 3; ++k) tf2x32(0u, 42u, 0u, (uint32_t)k, fk0[k], fk1[k]);

  const int B = 256;
  const int nb = (nn + 255) / 256;
  const int ne4 = (ne + 3) / 4;

  // d_ws layout (ints): counts[nn] | offsets[nn+1] | cursor[nn] | bsum[1024] | ecol[ne]
  size_t need = ((size_t)nn * 3 + 1 + 1024 + (size_t)ne) * sizeof(int) + 256;
  bool use_csr = (ws_size >= need) && (nb <= 1024);

  // out[0] = l2norm(x)
  l2norm_k<<<(nn * 16 + B - 1) / B, B, 0, stream>>>((const float4*)x, (float4*)out, nn);

  if (use_csr) {
    int* counts  = (int*)d_ws;
    int* offsets = counts + nn;
    int* cursor  = offsets + nn + 1;
    int* bsum    = cursor + nn;
    int* ecol    = bsum + 1024;

    zero_k<<<(nn + B - 1) / B, B, 0, stream>>>(counts, nn);
    hist_k<<<(ne4 + B - 1) / B, B, 0, stream>>>(row, counts, ne);
    blocksum_k<<<nb, 256, 0, stream>>>(counts, bsum, nn);
    scanb_k<<<1, 1024, 0, stream>>>(bsum, nb);
    offsets_k<<<nb, 256, 0, stream>>>(counts, bsum, offsets, cursor, nn);
    fill_k<<<(ne4 + B - 1) / B, B, 0, stream>>>(row, col, cursor, ecol, ne);

    for (int k = 0; k < 3; ++k) {
      const float* src = out + (size_t)k * total;
      float* dst = out + (size_t)(k + 1) * total;
      agg_k<<<(nn * 64 + B - 1) / B, B, 0, stream>>>(src, dst, offsets, ecol,
                                                     nn, fk0[k], fk1[k]);
    }
  } else {
    for (int k = 0; k < 3; ++k) {
      const float* src = out + (size_t)k * total;
      float* dst = out + (size_t)(k + 1) * total;
      noise_fill_k<<<(total + B - 1) / B, B, 0, stream>>>(dst, total, fk0[k], fk1[k]);
      scatter_k<<<(ne * 16 + B - 1) / B, B, 0, stream>>>(row, col, src, dst, ne);
      l2norm_k<<<(nn * 16 + B - 1) / B, B, 0, stream>>>((const float4*)dst, (float4*)dst, nn);
    }
  }
}

// Round 5
// 427.013 us; speedup vs baseline: 1.3655x; 1.3655x over previous
//
#include <hip/hip_runtime.h>
#include <cstdint>

// ---------------------------------------------------------------------------
// Threefry-2x32, 20 rounds — exact JAX schedule (jax/_src/prng.py)
// ---------------------------------------------------------------------------
static __host__ __device__ inline void tf2x32(uint32_t k0, uint32_t k1,
                                              uint32_t x0, uint32_t x1,
                                              uint32_t &o0, uint32_t &o1) {
  uint32_t ks2 = k0 ^ k1 ^ 0x1BD11BDAu;
  x0 += k0; x1 += k1;
#define TF_R(r) do { x0 += x1; x1 = (x1 << (r)) | (x1 >> (32 - (r))); x1 ^= x0; } while (0)
  TF_R(13); TF_R(15); TF_R(26); TF_R(6);
  x0 += k1; x1 += ks2 + 1u;
  TF_R(17); TF_R(29); TF_R(16); TF_R(24);
  x0 += ks2; x1 += k0 + 2u;
  TF_R(13); TF_R(15); TF_R(26); TF_R(6);
  x0 += k0; x1 += k1 + 3u;
  TF_R(17); TF_R(29); TF_R(16); TF_R(24);
  x0 += k1; x1 += ks2 + 4u;
  TF_R(13); TF_R(15); TF_R(26); TF_R(6);
  x0 += ks2; x1 += k0 + 5u;
#undef TF_R
  o0 = x0; o1 = x1;
}

// XLA's f32 erf_inv expansion (Giles poly, w = -log1p(-x*x)).
__device__ __forceinline__ float erfinv_xla_f32(float x) {
  float w = -log1pf(-x * x);
  float p;
  if (w < 5.0f) {
    w -= 2.5f;
    p = 2.81022636e-08f;
    p = fmaf(p, w, 3.43273939e-07f);
    p = fmaf(p, w, -3.5233877e-06f);
    p = fmaf(p, w, -4.39150654e-06f);
    p = fmaf(p, w, 0.00021858087f);
    p = fmaf(p, w, -0.00125372503f);
    p = fmaf(p, w, -0.00417768164f);
    p = fmaf(p, w, 0.246640727f);
    p = fmaf(p, w, 1.50140941f);
  } else {
    w = sqrtf(w) - 3.0f;
    p = -0.000200214257f;
    p = fmaf(p, w, 0.000100950558f);
    p = fmaf(p, w, 0.00134934322f);
    p = fmaf(p, w, -0.00367342844f);
    p = fmaf(p, w, 0.00573950773f);
    p = fmaf(p, w, -0.0076224613f);
    p = fmaf(p, w, 0.00943887047f);
    p = fmaf(p, w, 1.00167406f);
    p = fmaf(p, w, 2.83297682f);
  }
  return p * x;
}

__device__ __forceinline__ float noise_val(uint32_t kk0, uint32_t kk1, uint32_t idx) {
  uint32_t o0, o1;
  tf2x32(kk0, kk1, 0u, idx, o0, o1);
  uint32_t bits = o0 ^ o1;
  float u01 = __uint_as_float((bits >> 9) | 0x3f800000u) - 1.0f;
  const float LO = -0.99999994f;            // nextafter(-1f, 0f)
  float u = fmaxf(LO, fmaf(u01, 2.0f, LO)); // hi-lo rounds to exactly 2.0f
  return 0.1f * 1.41421356237f * erfinv_xla_f32(u);
}

__device__ __forceinline__ unsigned short f32_to_bf16_rne(float f) {
  uint32_t u = __float_as_uint(f);
  return (unsigned short)((u + 0x7fffu + ((u >> 16) & 1u)) >> 16);
}
__device__ __forceinline__ float bf16_to_f32(unsigned short h) {
  return __uint_as_float(((uint32_t)h) << 16);
}

// ---------------------------------------------------------------------------
// CSR build: counts -> 3-phase exclusive scan -> bucket fill  (R3-proven)
// ---------------------------------------------------------------------------
__global__ void zero_k(int* p, int n) {
  int i = blockIdx.x * blockDim.x + threadIdx.x;
  if (i < n) p[i] = 0;
}

__global__ void hist_k(const int* __restrict__ row, int* __restrict__ counts, int ne) {
  int e = blockIdx.x * blockDim.x + threadIdx.x;
  if (e < ne) atomicAdd(&counts[row[e]], 1);
}

__global__ void blocksum_k(const int* __restrict__ counts, int* __restrict__ bsum, int n) {
  int i = blockIdx.x * 256 + threadIdx.x;
  int v = (i < n) ? counts[i] : 0;
  for (int d = 1; d < 64; d <<= 1) v += __shfl_xor(v, d);
  __shared__ int ws[4];
  if ((threadIdx.x & 63) == 0) ws[threadIdx.x >> 6] = v;
  __syncthreads();
  if (threadIdx.x == 0) bsum[blockIdx.x] = ws[0] + ws[1] + ws[2] + ws[3];
}

__global__ void scanb_k(int* __restrict__ bsum, int nb) {
  __shared__ int tmp[1024];
  int t = threadIdx.x;
  int v = (t < nb) ? bsum[t] : 0;
  tmp[t] = v;
  __syncthreads();
  for (int d = 1; d < 1024; d <<= 1) {
    int x = (t >= d) ? tmp[t - d] : 0;
    __syncthreads();
    tmp[t] += x;
    __syncthreads();
  }
  if (t < nb) bsum[t] = tmp[t] - v;  // exclusive
}

__global__ void offsets_k(const int* __restrict__ counts, const int* __restrict__ bsumExcl,
                          int* __restrict__ offsets, int* __restrict__ cursor, int n) {
  int i = blockIdx.x * 256 + threadIdx.x;
  int v = (i < n) ? counts[i] : 0;
  __shared__ int tmp[256];
  tmp[threadIdx.x] = v;
  __syncthreads();
  for (int d = 1; d < 256; d <<= 1) {
    int x = (threadIdx.x >= d) ? tmp[threadIdx.x - d] : 0;
    __syncthreads();
    tmp[threadIdx.x] += x;
    __syncthreads();
  }
  int excl = tmp[threadIdx.x] - v + bsumExcl[blockIdx.x];
  if (i < n) { offsets[i] = excl; cursor[i] = excl; }
  if (i == n - 1) offsets[n] = excl + v;
}

__global__ void fill_k(const int* __restrict__ row, const int* __restrict__ col,
                       int* __restrict__ cursor, int* __restrict__ ecol, int ne) {
  int e = blockIdx.x * blockDim.x + threadIdx.x;
  if (e < ne) {
    int p = atomicAdd(&cursor[row[e]], 1);
    ecol[p] = col[e];
  }
}

// ---------------------------------------------------------------------------
// Fused per-hop kernel (R3 structure): one wave per dest row, 64 lanes = 64
// features, lane-parallel ecol preload + 8-deep gather pipeline.
// bf16 variant gathers 2B/lane (2 sectors/edge instead of 4) and emits both
// f32 output and a bf16 RNE side-copy for the next hop.
// ---------------------------------------------------------------------------
__global__ void agg_bf16_k(const unsigned short* __restrict__ srcb,
                           float* __restrict__ dst, unsigned short* __restrict__ dstb,
                           const int* __restrict__ offsets, const int* __restrict__ ecol,
                           int nn, uint32_t kk0, uint32_t kk1) {
  int w = (blockIdx.x * blockDim.x + threadIdx.x) >> 6;  // row = wave id
  int lane = threadIdx.x & 63;
  if (w >= nn) return;
  int beg = offsets[w], end = offsets[w + 1];
  int cnt = end - beg;
  float acc = 0.f;
  for (int base = 0; base < cnt; base += 64) {
    int m = cnt - base; if (m > 64) m = 64;
    int idx = base + lane;
    int myc = ecol[beg + (idx < cnt ? idx : cnt - 1)];   // 256B coalesced
    for (int j = 0; j < m; j += 8) {
      float v[8];
#pragma unroll
      for (int u = 0; u < 8; ++u) {
        int jj = j + u;
        int sl = jj < m ? jj : m - 1;        // uniform clamp -> valid address
        int c = __shfl(myc, sl);
        v[u] = bf16_to_f32(srcb[(size_t)c * 64 + lane]);  // 128B/edge, 8 in flight
      }
#pragma unroll
      for (int u = 0; u < 8; ++u)
        acc += (j + u < m) ? v[u] : 0.f;
    }
  }
  float nv = acc + noise_val(kk0, kk1, (uint32_t)(w * 64 + lane));
  float s = nv * nv;
  for (int d = 1; d < 64; d <<= 1) s += __shfl_xor(s, d);
  float inv = 1.0f / fmaxf(sqrtf(s), 1e-12f);
  float o = nv * inv;
  dst[(size_t)w * 64 + lane] = o;
  if (dstb) dstb[(size_t)w * 64 + lane] = f32_to_bf16_rne(o);
}

// f32 fallback agg (identical to R3's proven agg_k).
__global__ void agg_k(const float* __restrict__ src, float* __restrict__ dst,
                      const int* __restrict__ offsets, const int* __restrict__ ecol,
                      int nn, uint32_t kk0, uint32_t kk1) {
  int w = (blockIdx.x * blockDim.x + threadIdx.x) >> 6;
  int lane = threadIdx.x & 63;
  if (w >= nn) return;
  int beg = offsets[w], end = offsets[w + 1];
  int cnt = end - beg;
  float acc = 0.f;
  for (int base = 0; base < cnt; base += 64) {
    int m = cnt - base; if (m > 64) m = 64;
    int idx = base + lane;
    int myc = ecol[beg + (idx < cnt ? idx : cnt - 1)];
    for (int j = 0; j < m; j += 8) {
      float v[8];
#pragma unroll
      for (int u = 0; u < 8; ++u) {
        int jj = j + u;
        int sl = jj < m ? jj : m - 1;
        int c = __shfl(myc, sl);
        v[u] = src[(size_t)c * 64 + lane];
      }
#pragma unroll
      for (int u = 0; u < 8; ++u)
        acc += (j + u < m) ? v[u] : 0.f;
    }
  }
  float nv = acc + noise_val(kk0, kk1, (uint32_t)(w * 64 + lane));
  float s = nv * nv;
  for (int d = 1; d < 64; d <<= 1) s += __shfl_xor(s, d);
  float inv = 1.0f / fmaxf(sqrtf(s), 1e-12f);
  dst[(size_t)w * 64 + lane] = nv * inv;
}

// Row L2-normalize slice 0: 16 lanes/row, float4/lane; optional bf16 side-copy.
__global__ void l2norm_k(const float4* __restrict__ in, float4* __restrict__ out,
                         unsigned short* __restrict__ outb, int nrows) {
  int t = blockIdx.x * blockDim.x + threadIdx.x;
  int r = t >> 4, l = t & 15;
  if (r >= nrows) return;
  float4 v = in[(size_t)r * 16 + l];
  float s = v.x * v.x + v.y * v.y + v.z * v.z + v.w * v.w;
  s += __shfl_xor(s, 1);
  s += __shfl_xor(s, 2);
  s += __shfl_xor(s, 4);
  s += __shfl_xor(s, 8);
  float inv = 1.0f / fmaxf(sqrtf(s), 1e-12f);
  v.x *= inv; v.y *= inv; v.z *= inv; v.w *= inv;
  out[(size_t)r * 16 + l] = v;
  if (outb) {
    ushort4 h;
    h.x = f32_to_bf16_rne(v.x);
    h.y = f32_to_bf16_rne(v.y);
    h.z = f32_to_bf16_rne(v.z);
    h.w = f32_to_bf16_rne(v.w);
    ((ushort4*)outb)[(size_t)r * 16 + l] = h;
  }
}

// ---------------------------------------------------------------------------
// Fallback (atomic scatter) — only used if ws_size is too small for CSR.
// ---------------------------------------------------------------------------
__global__ void noise_fill_k(float* __restrict__ dst, int total,
                             uint32_t kk0, uint32_t kk1) {
  int i = blockIdx.x * blockDim.x + threadIdx.x;
  if (i < total) dst[i] = noise_val(kk0, kk1, (uint32_t)i);
}

__global__ void scatter_k(const int* __restrict__ row, const int* __restrict__ col,
                          const float* __restrict__ src, float* __restrict__ dst,
                          int ne) {
  int t = blockIdx.x * blockDim.x + threadIdx.x;
  int e = t >> 4, l = t & 15;
  if (e >= ne) return;
  int r = row[e], c = col[e];
  float4 v = ((const float4*)(src + (size_t)c * 64))[l];
  float* d = dst + (size_t)r * 64 + (size_t)l * 4;
  atomicAdd(d + 0, v.x);
  atomicAdd(d + 1, v.y);
  atomicAdd(d + 2, v.z);
  atomicAdd(d + 3, v.w);
}

static inline size_t align_up(size_t v, size_t a) { return (v + a - 1) & ~(a - 1); }

extern "C" void kernel_launch(void* const* d_in, const int* in_sizes, int n_in,
                              void* d_out, int out_size, void* d_ws, size_t ws_size,
                              hipStream_t stream) {
  const float* x = (const float*)d_in[0];
  const int* ei = (const int*)d_in[1];
  float* out = (float*)d_out;

  const int nn = in_sizes[0] / 64;     // 100000
  const int ne = in_sizes[1] / 2;     // 1600000
  const int total = nn * 64;
  const int* row = ei;
  const int* col = ei + ne;

  // Per-hop fold_in keys: threefry2x32((0,42), (0,k)) — host precompute.
  uint32_t fk0[3], fk1[3];
  for (int k = 0; k < 3; ++k) tf2x32(0u, 42u, 0u, (uint32_t)k, fk0[k], fk1[k]);

  const int B = 256;
  const int nb = (nn + 255) / 256;

  // ws layout: counts[nn] | offsets[nn+1] | cursor[nn] | bsum[1024] | ecol[ne]
  //            | (align 16) bf16 bufA[total] | bf16 bufB[total]
  size_t csr_bytes = ((size_t)nn * 3 + 1 + 1024 + (size_t)ne) * sizeof(int);
  size_t bf_off = align_up(csr_bytes, 16);
  size_t need_csr = csr_bytes + 256;
  size_t need_bf16 = bf_off + 2 * (size_t)total * sizeof(unsigned short) + 256;
  bool use_csr = (ws_size >= need_csr) && (nb <= 1024);
  bool use_bf16 = use_csr && (ws_size >= need_bf16);

  if (use_csr) {
    int* counts  = (int*)d_ws;
    int* offsets = counts + nn;
    int* cursor  = offsets + nn + 1;
    int* bsum    = cursor + nn;
    int* ecol    = bsum + 1024;
    unsigned short* bufA = (unsigned short*)((char*)d_ws + bf_off);
    unsigned short* bufB = bufA + total;

    // out[0] = l2norm(x) (+ bf16 copy for hop 1 gathers)
    l2norm_k<<<(nn * 16 + B - 1) / B, B, 0, stream>>>(
        (const float4*)x, (float4*)out, use_bf16 ? bufA : nullptr, nn);

    zero_k<<<(nn + B - 1) / B, B, 0, stream>>>(counts, nn);
    hist_k<<<(ne + B - 1) / B, B, 0, stream>>>(row, counts, ne);
    blocksum_k<<<nb, 256, 0, stream>>>(counts, bsum, nn);
    scanb_k<<<1, 1024, 0, stream>>>(bsum, nb);
    offsets_k<<<nb, 256, 0, stream>>>(counts, bsum, offsets, cursor, nn);
    fill_k<<<(ne + B - 1) / B, B, 0, stream>>>(row, col, cursor, ecol, ne);

    for (int k = 0; k < 3; ++k) {
      float* dst = out + (size_t)(k + 1) * total;
      if (use_bf16) {
        unsigned short* sb = (k & 1) ? bufB : bufA;
        unsigned short* db = (k == 2) ? nullptr : ((k & 1) ? bufA : bufB);
        agg_bf16_k<<<(nn * 64 + B - 1) / B, B, 0, stream>>>(
            sb, dst, db, offsets, ecol, nn, fk0[k], fk1[k]);
      } else {
        const float* src = out + (size_t)k * total;
        agg_k<<<(nn * 64 + B - 1) / B, B, 0, stream>>>(
            src, dst, offsets, ecol, nn, fk0[k], fk1[k]);
      }
    }
  } else {
    l2norm_k<<<(nn * 16 + B - 1) / B, B, 0, stream>>>(
        (const float4*)x, (float4*)out, nullptr, nn);
    for (int k = 0; k < 3; ++k) {
      const float* src = out + (size_t)k * total;
      float* dst = out + (size_t)(k + 1) * total;
      noise_fill_k<<<(total + B - 1) / B, B, 0, stream>>>(dst, total, fk0[k], fk1[k]);
      scatter_k<<<(ne * 16 + B - 1) / B, B, 0, stream>>>(row, col, src, dst, ne);
      l2norm_k<<<(nn * 16 + B - 1) / B, B, 0, stream>>>(
          (const float4*)dst, (float4*)dst, nullptr, nn);
    }
  }
}